// Round 1
// baseline (18.245 us; speedup 1.0000x reference)
//
#include <hip/hip_runtime.h>
#include <math.h>

#define QK_N_LAYERS 3
#define QK_N_WIRES  4

// Kernel 1: one thread computes c^2 = (prod_{l,w,k} cos(theta[l,w,k]/2))^2
// in double precision, stores a single float into workspace.
__global__ void qk_compute_scalar(const float* __restrict__ theta,
                                  float* __restrict__ ws) {
    if (blockIdx.x == 0 && threadIdx.x == 0) {
        double c = 1.0;
        #pragma unroll
        for (int i = 0; i < QK_N_LAYERS * QK_N_WIRES * 2; ++i) {
            c *= cos((double)theta[i] * 0.5);
        }
        ws[0] = (float)(c * c);
    }
}

// Kernel 2: broadcast-fill. Row i of the (B,4) output is [c2, 0, 0, 0].
// One float4 store per thread, fully coalesced (16 B/lane).
__global__ void qk_fill(const float* __restrict__ ws,
                        float4* __restrict__ out, int B) {
    int i = blockIdx.x * blockDim.x + threadIdx.x;
    float c2 = ws[0];
    if (i < B) {
        out[i] = make_float4(c2, 0.0f, 0.0f, 0.0f);
    }
}

extern "C" void kernel_launch(void* const* d_in, const int* in_sizes, int n_in,
                              void* d_out, int out_size, void* d_ws, size_t ws_size,
                              hipStream_t stream) {
    // inputs: d_in[0] = patch (B,4) f32 [unused numerically], d_in[1] = theta (3,4,2) f32
    const float* theta = (const float*)d_in[1];
    float* ws = (float*)d_ws;
    float4* out = (float4*)d_out;

    const int B = in_sizes[0] / 4;  // patch has B*4 elements

    qk_compute_scalar<<<1, 64, 0, stream>>>(theta, ws);

    const int block = 256;
    const int grid = (B + block - 1) / block;
    qk_fill<<<grid, block, 0, stream>>>(ws, out, B);
}

// Round 2
// 11.992 us; speedup vs baseline: 1.5214x; 1.5214x over previous
//
#include <hip/hip_runtime.h>
#include <math.h>

#define QK_NTHETA 24   // N_LAYERS(3) * N_WIRES(4) * 2

// Fused: every wave computes c = prod cos(theta_i/2) lane-parallel, then
// broadcast-fills rows of the (B,4) output with [c^2, 0, 0, 0].
__global__ void qk_fused(const float* __restrict__ theta,
                         float4* __restrict__ out, int B) {
    const int lane = threadIdx.x & 63;

    // lanes 0..23 each compute one cosine; others contribute 1.0
    float v = 1.0f;
    if (lane < QK_NTHETA) {
        v = cosf(theta[lane] * 0.5f);
    }
    // 64-lane product reduction (butterfly)
    #pragma unroll
    for (int off = 1; off < 64; off <<= 1) {
        v *= __shfl_xor(v, off, 64);
    }
    const float c2 = v * v;
    const float4 row = make_float4(c2, 0.0f, 0.0f, 0.0f);

    // grid-stride broadcast store, one float4 (16 B) per iteration per lane
    const int stride = gridDim.x * blockDim.x;
    for (int i = blockIdx.x * blockDim.x + threadIdx.x; i < B; i += stride) {
        out[i] = row;
    }
}

extern "C" void kernel_launch(void* const* d_in, const int* in_sizes, int n_in,
                              void* d_out, int out_size, void* d_ws, size_t ws_size,
                              hipStream_t stream) {
    // d_in[0] = patch (B,4) f32 [numerically unused], d_in[1] = theta (3,4,2) f32
    const float* theta = (const float*)d_in[1];
    float4* out = (float4*)d_out;

    const int B = in_sizes[0] / 4;

    const int block = 256;
    int grid = (B + block - 1) / block;
    if (grid > 2048) grid = 2048;   // grid-stride the rest
    qk_fused<<<grid, block, 0, stream>>>(theta, out, B);
}

// Round 3
// 11.274 us; speedup vs baseline: 1.6183x; 1.0637x over previous
//
#include <hip/hip_runtime.h>
#include <math.h>

#define QK_NTHETA 24   // N_LAYERS(3) * N_WIRES(4) * 2

// Fused single-dispatch kernel: every wave computes c = prod cos(theta_i/2)
// lane-parallel (lanes 0..23, others contribute 1.0), butterfly-reduces the
// product, then each thread stores exactly one row [c^2,0,0,0] of the (B,4)
// output as one float4. Exact grid: no grid-stride loop.
__global__ void __launch_bounds__(512) qk_fused(const float* __restrict__ theta,
                                                float4* __restrict__ out, int B) {
    const int lane = threadIdx.x & 63;

    float v = 1.0f;
    if (lane < QK_NTHETA) {
        v = cosf(theta[lane] * 0.5f);
    }
    #pragma unroll
    for (int off = 1; off < 64; off <<= 1) {
        v *= __shfl_xor(v, off, 64);
    }
    const float c2 = v * v;

    const int i = blockIdx.x * blockDim.x + threadIdx.x;
    if (i < B) {
        out[i] = make_float4(c2, 0.0f, 0.0f, 0.0f);
    }
}

extern "C" void kernel_launch(void* const* d_in, const int* in_sizes, int n_in,
                              void* d_out, int out_size, void* d_ws, size_t ws_size,
                              hipStream_t stream) {
    // d_in[0] = patch (B,4) f32 [numerically unused], d_in[1] = theta (3,4,2) f32
    const float* theta = (const float*)d_in[1];
    float4* out = (float4*)d_out;

    const int B = in_sizes[0] / 4;  // patch has B*4 elements

    const int block = 512;
    const int grid = (B + block - 1) / block;  // exact: one row per thread
    qk_fused<<<grid, block, 0, stream>>>(theta, out, B);
}